// Round 3
// baseline (448.794 us; speedup 1.0000x reference)
//
#include <hip/hip_runtime.h>
#include <hip/hip_cooperative_groups.h>
#include <math.h>

namespace cg = cooperative_groups;

#define NN 512
#define HH 64
#define NLAYERS 4
#define LN_EPS 1e-5f

// ===========================================================================
// Fused cooperative kernel: block j owns dst node j end-to-end.
//   LDS-resident across all layers: ea_s (edge attrs, scatter-loaded once),
//   hs (node state), pd_s (dst attention part).
//   Global per-layer exchange (written by prep, read by all blocks after
//   grid.sync): Qs, Rv (NN*HH) and Sq (NN).
// Algebra (validated round 2, absmax 0.0):
//   z_att[u](i,j) = Pd[j,u] + Qs[i,u] + ea(j,i)·WA[:,u]
//   score(i,j)    = 0.6*Sq[i] + ea·w6s + sum_u |z|*0.4*wa2[u]   (+dst-consts dropped)
//   acc[j]        = sum_i alpha * relu(Rv[i] + ea·WV);  agg = acc@val_w2 + vb2
// ===========================================================================

struct GnnParams {
    const float *x, *ea;
    const float *ew1, *eb1, *ew2, *eb2;
    const float *aw1, *ab1, *aw2;
    const float *vw1, *vb1, *vw2, *vb2;
    const float *uw1, *ub1, *uw2, *ub2;
    const float *lng, *lnb;
    const float *dw1, *db1, *dw2, *db2;
    float *Qs, *Rv, *Sq, *out;
};

__launch_bounds__(256, 2)
__global__ void k_fused(GnnParams P) {
    cg::grid_group grid = cg::this_grid();
    const int j = blockIdx.x;
    const int tid = threadIdx.x;
    const int lane = tid & 63;
    const int w = tid >> 6;        // wave 0..3
    const int slot = lane >> 3;    // 0..7 (src sub-index)
    const int dp = lane & 7;       // 0..7 (dim part)
    const int d0 = dp * 8;
    const int d = lane;            // dim index for node phases

    __shared__ __align__(16) float ea_s[NN * 6];   // 12 KB, resident all layers
    __shared__ __align__(16) float Sq_s[NN];
    __shared__ float a_s[NN];
    __shared__ float hs[HH], pd_s[HH], av[HH], uin[2 * HH], r1[HH];
    __shared__ float part[4][HH], partQ[4][HH], partR[4][HH];
    __shared__ float red_m[4], red_s[4];
    __shared__ float accs[4][HH];

    // ---- stage edge attrs for dst j (scattered read, once, reused 4 layers) ----
#pragma unroll
    for (int rep = 0; rep < 2; ++rep) {
        int i = tid + rep * 256;
        const float2* s2 = (const float2*)(P.ea + ((size_t)i * NN + j) * 6);
        float2 a0 = s2[0], a1 = s2[1], a2 = s2[2];
        ea_s[i * 6 + 0] = a0.x; ea_s[i * 6 + 1] = a0.y;
        ea_s[i * 6 + 2] = a1.x; ea_s[i * 6 + 3] = a1.y;
        ea_s[i * 6 + 4] = a2.x; ea_s[i * 6 + 5] = a2.y;
    }

    // ---- encoder: hs = relu(x@ew1+eb1)@ew2+eb2 ----
    if (w == 0) {
        float z = P.eb1[d];
#pragma unroll
        for (int k = 0; k < 6; ++k) z += P.x[j * 6 + k] * P.ew1[k * HH + d];
        r1[d] = fmaxf(z, 0.f);
    }
    __syncthreads();
    {
        float z2 = (w == 0) ? P.eb2[d] : 0.f;
        for (int k = w * 16; k < w * 16 + 16; ++k) z2 += r1[k] * P.ew2[k * HH + d];
        part[w][d] = z2;
    }
    __syncthreads();
    if (w == 0) hs[d] = part[0][d] + part[1][d] + part[2][d] + part[3][d];
    __syncthreads();

    // ---- prep(l): pd_s (LDS) + Qs/Rv/Sq (global) from hs ----
    auto do_prep = [&](int l) {
        const float* a1p = P.aw1 + (size_t)l * 134 * HH;
        const float* v1p = P.vw1 + (size_t)l * 70 * HH;
        float pp = (w == 0) ? P.ab1[l * HH + d] : 0.f;
        float qq = 0.f;
        float rr = (w == 0) ? P.vb1[l * HH + d] : 0.f;
        for (int k = w * 16; k < w * 16 + 16; ++k) {
            float hk = hs[k];
            pp += hk * a1p[k * HH + d];
            qq += hk * a1p[(HH + k) * HH + d];
            rr += hk * v1p[k * HH + d];
        }
        part[w][d] = pp; partQ[w][d] = qq; partR[w][d] = rr;
        __syncthreads();
        if (w == 0) {
            float qf = partQ[0][d] + partQ[1][d] + partQ[2][d] + partQ[3][d];
            pd_s[d] = part[0][d] + part[1][d] + part[2][d] + part[3][d];
            P.Qs[(size_t)j * HH + d] = qf;
            P.Rv[(size_t)j * HH + d] = partR[0][d] + partR[1][d] + partR[2][d] + partR[3][d];
            float sq = qf * P.aw2[l * HH + d];
#pragma unroll
            for (int o = 32; o; o >>= 1) sq += __shfl_xor(sq, o);
            if (d == 0) P.Sq[j] = sq;
        }
        __syncthreads();
    };

    do_prep(0);
    grid.sync();

    for (int l = 0; l < NLAYERS; ++l) {
        const float* a1p = P.aw1 + (size_t)l * 134 * HH;
        const float* waE = a1p + 128 * HH;                       // 6x64 edge rows
        const float* wvE = P.vw1 + (size_t)l * 70 * HH + 64 * HH;
        const float* wa2v = P.aw2 + l * HH;

        // ================= edge phase =================
        if (tid < 128) ((float4*)Sq_s)[tid] = ((const float4*)P.Sq)[tid];
        float WA[6][8], wa2raw[8], wa2r[8], pdr[8], w6s[6];
#pragma unroll
        for (int k = 0; k < 6; ++k)
#pragma unroll
            for (int u = 0; u < 8; ++u) WA[k][u] = waE[k * HH + d0 + u];
#pragma unroll
        for (int u = 0; u < 8; ++u) {
            wa2raw[u] = wa2v[d0 + u];
            pdr[u] = pd_s[d0 + u];
        }
#pragma unroll
        for (int k = 0; k < 6; ++k) {
            float t = 0.f;
#pragma unroll
            for (int u = 0; u < 8; ++u) t += WA[k][u] * wa2raw[u];
            t += __shfl_xor(t, 1);
            t += __shfl_xor(t, 2);
            t += __shfl_xor(t, 4);
            w6s[k] = 0.6f * t;
        }
#pragma unroll
        for (int u = 0; u < 8; ++u) wa2r[u] = 0.4f * wa2raw[u];
        __syncthreads();   // Sq_s ready; a_s free for reuse

        const int ibw = w * 128;
        float lmax = -1e30f;
#pragma unroll 2
        for (int it = 0; it < 16; ++it) {
            const int i = ibw + it * 8 + slot;
            const float4* q4 = (const float4*)(P.Qs + (size_t)i * HH + d0);
            float4 qa = q4[0], qb = q4[1];
            float qv[8] = {qa.x, qa.y, qa.z, qa.w, qb.x, qb.y, qb.z, qb.w};
            float eav[6];
#pragma unroll
            for (int k = 0; k < 6; ++k) eav[k] = ea_s[i * 6 + k];
            float p1 = 0.f;
#pragma unroll
            for (int u = 0; u < 8; ++u) {
                float z = pdr[u] + qv[u];
#pragma unroll
                for (int k = 0; k < 6; ++k) z += eav[k] * WA[k][u];
                p1 += fabsf(z) * wa2r[u];
            }
            p1 += __shfl_xor(p1, 1);
            p1 += __shfl_xor(p1, 2);
            p1 += __shfl_xor(p1, 4);
            float lin = 0.6f * Sq_s[i];
#pragma unroll
            for (int k = 0; k < 6; ++k) lin += eav[k] * w6s[k];
            float a = lin + p1;
            if (dp == 0) a_s[i] = a;
            lmax = fmaxf(lmax, a);
        }
#pragma unroll
        for (int o = 32; o; o >>= 1) lmax = fmaxf(lmax, __shfl_xor(lmax, o));
        if (lane == 0) red_m[w] = lmax;
        __syncthreads();
        const float m = fmaxf(fmaxf(red_m[0], red_m[1]), fmaxf(red_m[2], red_m[3]));
        float lsum = 0.f;
#pragma unroll
        for (int rep = 0; rep < 2; ++rep) {
            int i = tid + rep * 256;
            float e = expf(a_s[i] - m);
            a_s[i] = e;
            lsum += e;
        }
#pragma unroll
        for (int o = 32; o; o >>= 1) lsum += __shfl_xor(lsum, o);
        if (lane == 0) red_s[w] = lsum;
        __syncthreads();
        const float s = red_s[0] + red_s[1] + red_s[2] + red_s[3];

        float WV[6][8];   // deferred load: keeps phase-1 VGPR pressure low
#pragma unroll
        for (int k = 0; k < 6; ++k)
#pragma unroll
            for (int u = 0; u < 8; ++u) WV[k][u] = wvE[k * HH + d0 + u];
        float acc[8] = {0.f, 0.f, 0.f, 0.f, 0.f, 0.f, 0.f, 0.f};
#pragma unroll 2
        for (int it = 0; it < 16; ++it) {
            const int i = ibw + it * 8 + slot;
            const float4* r4 = (const float4*)(P.Rv + (size_t)i * HH + d0);
            float4 ra = r4[0], rb = r4[1];
            float rv[8] = {ra.x, ra.y, ra.z, ra.w, rb.x, rb.y, rb.z, rb.w};
            float eav[6];
#pragma unroll
            for (int k = 0; k < 6; ++k) eav[k] = ea_s[i * 6 + k];
            const float wi = a_s[i];
#pragma unroll
            for (int u = 0; u < 8; ++u) {
                float z = rv[u];
#pragma unroll
                for (int k = 0; k < 6; ++k) z += eav[k] * WV[k][u];
                acc[u] += wi * fmaxf(z, 0.f);
            }
        }
#pragma unroll
        for (int u = 0; u < 8; ++u) {
            acc[u] += __shfl_xor(acc[u], 8);
            acc[u] += __shfl_xor(acc[u], 16);
            acc[u] += __shfl_xor(acc[u], 32);
        }
        if (slot == 0) {
#pragma unroll
            for (int u = 0; u < 8; ++u) accs[w][d0 + u] = acc[u];
        }
        __syncthreads();
        if (tid < HH) av[tid] = (accs[0][tid] + accs[1][tid] + accs[2][tid] + accs[3][tid]) / s;
        __syncthreads();

        // ================= node phase =================
        const float* wv2 = P.vw2 + (size_t)l * HH * HH;
        const float* uw1 = P.uw1 + (size_t)l * 2 * HH * HH;
        const float* uw2 = P.uw2 + (size_t)l * HH * HH;
        float hv = hs[d];
        if (w == 0) uin[d] = hv;
        {
            float p = (w == 0) ? P.vb2[l * HH + d] : 0.f;
            for (int k = w * 16; k < w * 16 + 16; ++k) p += av[k] * wv2[k * HH + d];
            part[w][d] = p;
        }
        __syncthreads();
        if (w == 0) uin[HH + d] = part[0][d] + part[1][d] + part[2][d] + part[3][d];
        __syncthreads();
        {
            float t = (w == 0) ? P.ub1[l * HH + d] : 0.f;
            for (int c = w * 32; c < w * 32 + 32; ++c) t += uin[c] * uw1[c * HH + d];
            part[w][d] = t;
        }
        __syncthreads();
        if (w == 0) r1[d] = fmaxf(part[0][d] + part[1][d] + part[2][d] + part[3][d], 0.f);
        __syncthreads();
        {
            float u = (w == 0) ? P.ub2[l * HH + d] : 0.f;
            for (int k = w * 16; k < w * 16 + 16; ++k) u += r1[k] * uw2[k * HH + d];
            part[w][d] = u;
        }
        __syncthreads();
        float r = part[0][d] + part[1][d] + part[2][d] + part[3][d] + hv;
        float sum = r;
#pragma unroll
        for (int o = 32; o; o >>= 1) sum += __shfl_xor(sum, o);
        float mu = sum * (1.f / HH);
        float dr = r - mu;
        float v2 = dr * dr;
#pragma unroll
        for (int o = 32; o; o >>= 1) v2 += __shfl_xor(v2, o);
        float var = v2 * (1.f / HH);
        float hn = P.lng[l * HH + d] * dr * (1.f / sqrtf(var + LN_EPS)) + P.lnb[l * HH + d];
        __syncthreads();              // all reads of part[][]/old hs complete
        if (w == 0) hs[d] = hn;
        __syncthreads();

        if (l + 1 < NLAYERS) {
            do_prep(l + 1);
            grid.sync();
        }
    }

    // ================= decoder =================
    {
        float t = (w == 0) ? P.db1[d] : 0.f;
        for (int k = w * 16; k < w * 16 + 16; ++k) t += hs[k] * P.dw1[k * HH + d];
        part[w][d] = t;
    }
    __syncthreads();
    if (w == 0) {
        float tt = fmaxf(part[0][d] + part[1][d] + part[2][d] + part[3][d], 0.f);
        float sum = tt * P.dw2[d];
#pragma unroll
        for (int o = 32; o; o >>= 1) sum += __shfl_xor(sum, o);
        if (d == 0) P.out[j] = sum + P.db2[0];
    }
}

// ===========================================================================
// Fallback path (round-2 validated multi-kernel pipeline) — used only if the
// cooperative launch is rejected by the runtime/capture.
// ===========================================================================

__global__ void k_transpose(const float* __restrict__ ea, float* __restrict__ eat) {
    int t = blockIdx.x * 256 + threadIdx.x;
    int i = t & (NN - 1);
    int j = t >> 9;
    int e = i * NN + j;
#pragma unroll
    for (int k = 0; k < 6; ++k) eat[(size_t)t * 6 + k] = ea[(size_t)e * 6 + k];
}

__global__ void k_encoder(const float* __restrict__ x,
                          const float* __restrict__ ew1, const float* __restrict__ eb1,
                          const float* __restrict__ ew2, const float* __restrict__ eb2,
                          const float* __restrict__ aw1, const float* __restrict__ ab1,
                          const float* __restrict__ wa2, const float* __restrict__ vw1,
                          const float* __restrict__ vb1,
                          float* __restrict__ h, float* __restrict__ Pd,
                          float* __restrict__ Qs, float* __restrict__ Rv,
                          float* __restrict__ Sq) {
    int j = blockIdx.x, d = threadIdx.x;
    __shared__ float xs[6], t1[HH], hs[HH];
    if (d < 6) xs[d] = x[j * 6 + d];
    __syncthreads();
    float z = eb1[d];
#pragma unroll
    for (int k = 0; k < 6; ++k) z += xs[k] * ew1[k * HH + d];
    t1[d] = fmaxf(z, 0.f);
    __syncthreads();
    float z2 = eb2[d];
    for (int k = 0; k < HH; ++k) z2 += t1[k] * ew2[k * HH + d];
    h[j * HH + d] = z2;
    hs[d] = z2;
    __syncthreads();
    float p = ab1[d], q = 0.f, r = vb1[d];
    for (int k = 0; k < HH; ++k) {
        float hv = hs[k];
        p += hv * aw1[k * HH + d];
        q += hv * aw1[(HH + k) * HH + d];
        r += hv * vw1[k * HH + d];
    }
    Pd[j * HH + d] = p;
    Qs[j * HH + d] = q;
    Rv[j * HH + d] = r;
    float sq = q * wa2[d];
#pragma unroll
    for (int o = 32; o; o >>= 1) sq += __shfl_xor(sq, o);
    if (d == 0) Sq[j] = sq;
}

__launch_bounds__(256)
__global__ void k_edge_fb(const float* __restrict__ eat,
                          const float* __restrict__ Pd, const float* __restrict__ Qs,
                          const float* __restrict__ Rv, const float* __restrict__ Sq,
                          const float* __restrict__ waE, const float* __restrict__ wa2v,
                          const float* __restrict__ wvE, float* __restrict__ accv) {
    const int j = blockIdx.x;
    const int tid = threadIdx.x;
    const int lane = tid & 63;
    const int w = tid >> 6;
    const int slot = lane >> 3;
    const int dp = lane & 7;
    const int d0 = dp * 8;

    __shared__ __align__(16) float ea_s[NN * 6];
    __shared__ __align__(16) float Sq_s[NN];
    __shared__ float a_s[NN];
    __shared__ float red_m[4], red_s[4];
    __shared__ float accs[4][HH];

    {
        const float4* s4 = (const float4*)(eat + (size_t)j * (NN * 6));
        float4* d4 = (float4*)ea_s;
#pragma unroll
        for (int p = 0; p < 3; ++p) d4[tid + 256 * p] = s4[tid + 256 * p];
    }
    if (tid < 128) ((float4*)Sq_s)[tid] = ((const float4*)Sq)[tid];

    float WA[6][8], WV[6][8], wa2raw[8], wa2r[8], pdr[8];
#pragma unroll
    for (int k = 0; k < 6; ++k)
#pragma unroll
        for (int u = 0; u < 8; ++u) {
            WA[k][u] = waE[k * HH + d0 + u];
            WV[k][u] = wvE[k * HH + d0 + u];
        }
#pragma unroll
    for (int u = 0; u < 8; ++u) {
        wa2raw[u] = wa2v[d0 + u];
        pdr[u] = Pd[(size_t)j * HH + d0 + u];
    }
    float w6s[6];
#pragma unroll
    for (int k = 0; k < 6; ++k) {
        float t = 0.f;
#pragma unroll
        for (int u = 0; u < 8; ++u) t += WA[k][u] * wa2raw[u];
        t += __shfl_xor(t, 1);
        t += __shfl_xor(t, 2);
        t += __shfl_xor(t, 4);
        w6s[k] = 0.6f * t;
    }
#pragma unroll
    for (int u = 0; u < 8; ++u) wa2r[u] = 0.4f * wa2raw[u];
    __syncthreads();

    const int ibw = w * 128;
    float lmax = -1e30f;
    for (int it = 0; it < 16; ++it) {
        const int i = ibw + it * 8 + slot;
        const float4* q4 = (const float4*)(Qs + (size_t)i * HH + d0);
        float4 qa = q4[0], qb = q4[1];
        float qv[8] = {qa.x, qa.y, qa.z, qa.w, qb.x, qb.y, qb.z, qb.w};
        float eav[6];
#pragma unroll
        for (int k = 0; k < 6; ++k) eav[k] = ea_s[i * 6 + k];
        float part = 0.f;
#pragma unroll
        for (int u = 0; u < 8; ++u) {
            float z = pdr[u] + qv[u];
#pragma unroll
            for (int k = 0; k < 6; ++k) z += eav[k] * WA[k][u];
            part += fabsf(z) * wa2r[u];
        }
        part += __shfl_xor(part, 1);
        part += __shfl_xor(part, 2);
        part += __shfl_xor(part, 4);
        float lin = 0.6f * Sq_s[i];
#pragma unroll
        for (int k = 0; k < 6; ++k) lin += eav[k] * w6s[k];
        float a = lin + part;
        if (dp == 0) a_s[i] = a;
        lmax = fmaxf(lmax, a);
    }
#pragma unroll
    for (int o = 32; o; o >>= 1) lmax = fmaxf(lmax, __shfl_xor(lmax, o));
    if (lane == 0) red_m[w] = lmax;
    __syncthreads();
    const float m = fmaxf(fmaxf(red_m[0], red_m[1]), fmaxf(red_m[2], red_m[3]));
    float lsum = 0.f;
#pragma unroll
    for (int rep = 0; rep < 2; ++rep) {
        int i = tid + rep * 256;
        float e = expf(a_s[i] - m);
        a_s[i] = e;
        lsum += e;
    }
#pragma unroll
    for (int o = 32; o; o >>= 1) lsum += __shfl_xor(lsum, o);
    if (lane == 0) red_s[w] = lsum;
    __syncthreads();
    const float s = red_s[0] + red_s[1] + red_s[2] + red_s[3];

    float acc[8] = {0.f, 0.f, 0.f, 0.f, 0.f, 0.f, 0.f, 0.f};
    for (int it = 0; it < 16; ++it) {
        const int i = ibw + it * 8 + slot;
        const float4* r4 = (const float4*)(Rv + (size_t)i * HH + d0);
        float4 ra = r4[0], rb = r4[1];
        float rv[8] = {ra.x, ra.y, ra.z, ra.w, rb.x, rb.y, rb.z, rb.w};
        float eav[6];
#pragma unroll
        for (int k = 0; k < 6; ++k) eav[k] = ea_s[i * 6 + k];
        const float wi = a_s[i];
#pragma unroll
        for (int u = 0; u < 8; ++u) {
            float z = rv[u];
#pragma unroll
            for (int k = 0; k < 6; ++k) z += eav[k] * WV[k][u];
            acc[u] += wi * fmaxf(z, 0.f);
        }
    }
#pragma unroll
    for (int u = 0; u < 8; ++u) {
        acc[u] += __shfl_xor(acc[u], 8);
        acc[u] += __shfl_xor(acc[u], 16);
        acc[u] += __shfl_xor(acc[u], 32);
    }
    if (slot == 0) {
#pragma unroll
        for (int u = 0; u < 8; ++u) accs[w][d0 + u] = acc[u];
    }
    __syncthreads();
    if (tid < HH) {
        float tot = (accs[0][tid] + accs[1][tid] + accs[2][tid] + accs[3][tid]) / s;
        accv[(size_t)j * HH + tid] = tot;
    }
}

__launch_bounds__(256)
__global__ void k_node_fb(const float* __restrict__ h_in, const float* __restrict__ accv,
                          const float* __restrict__ wv2, const float* __restrict__ vb2,
                          const float* __restrict__ uw1, const float* __restrict__ ub1,
                          const float* __restrict__ uw2, const float* __restrict__ ub2,
                          const float* __restrict__ lng, const float* __restrict__ lnb,
                          float* __restrict__ h_out,
                          const float* __restrict__ aw1n, const float* __restrict__ ab1n,
                          const float* __restrict__ wa2n, const float* __restrict__ vw1n,
                          const float* __restrict__ vb1n,
                          float* __restrict__ Pd, float* __restrict__ Qs,
                          float* __restrict__ Rv, float* __restrict__ Sq,
                          int do_prep) {
    const int j = blockIdx.x;
    const int tid = threadIdx.x;
    const int d = tid & 63;
    const int w = tid >> 6;
    __shared__ float av[HH], uin[2 * HH], r1[HH], hs[HH];
    __shared__ float part[4][HH], partQ[4][HH], partR[4][HH];

    float hv = h_in[(size_t)j * HH + d];
    if (w == 0) { av[d] = accv[(size_t)j * HH + d]; uin[d] = hv; }
    __syncthreads();
    float p = (w == 0) ? vb2[d] : 0.f;
    for (int k = w * 16; k < w * 16 + 16; ++k) p += av[k] * wv2[k * HH + d];
    part[w][d] = p;
    __syncthreads();
    if (w == 0) uin[HH + d] = part[0][d] + part[1][d] + part[2][d] + part[3][d];
    __syncthreads();
    float t = (w == 0) ? ub1[d] : 0.f;
    for (int c = w * 32; c < w * 32 + 32; ++c) t += uin[c] * uw1[c * HH + d];
    part[w][d] = t;
    __syncthreads();
    if (w == 0) r1[d] = fmaxf(part[0][d] + part[1][d] + part[2][d] + part[3][d], 0.f);
    __syncthreads();
    float u = (w == 0) ? ub2[d] : 0.f;
    for (int k = w * 16; k < w * 16 + 16; ++k) u += r1[k] * uw2[k * HH + d];
    part[w][d] = u;
    __syncthreads();
    float uu = part[0][d] + part[1][d] + part[2][d] + part[3][d];
    float r = uu + hv;
    float sum = r;
#pragma unroll
    for (int o = 32; o; o >>= 1) sum += __shfl_xor(sum, o);
    float mu = sum * (1.f / HH);
    float dr = r - mu;
    float v2 = dr * dr;
#pragma unroll
    for (int o = 32; o; o >>= 1) v2 += __shfl_xor(v2, o);
    float var = v2 * (1.f / HH);
    float hn = lng[d] * dr * (1.f / sqrtf(var + LN_EPS)) + lnb[d];
    if (w == 0) { h_out[(size_t)j * HH + d] = hn; hs[d] = hn; }
    __syncthreads();
    if (do_prep) {
        float pp = (w == 0) ? ab1n[d] : 0.f, qq = 0.f, rr = (w == 0) ? vb1n[d] : 0.f;
        for (int k = w * 16; k < w * 16 + 16; ++k) {
            float hk = hs[k];
            pp += hk * aw1n[k * HH + d];
            qq += hk * aw1n[(HH + k) * HH + d];
            rr += hk * vw1n[k * HH + d];
        }
        part[w][d] = pp; partQ[w][d] = qq; partR[w][d] = rr;
        __syncthreads();
        float qfull = partQ[0][d] + partQ[1][d] + partQ[2][d] + partQ[3][d];
        if (w == 0) {
            Pd[(size_t)j * HH + d] = part[0][d] + part[1][d] + part[2][d] + part[3][d];
            Qs[(size_t)j * HH + d] = qfull;
            Rv[(size_t)j * HH + d] = partR[0][d] + partR[1][d] + partR[2][d] + partR[3][d];
            float sq = qfull * wa2n[d];
#pragma unroll
            for (int o = 32; o; o >>= 1) sq += __shfl_xor(sq, o);
            if (d == 0) Sq[j] = sq;
        }
    }
}

__global__ void k_decoder(const float* __restrict__ h,
                          const float* __restrict__ dw1, const float* __restrict__ db1,
                          const float* __restrict__ dw2, const float* __restrict__ db2,
                          float* __restrict__ out) {
    int j = blockIdx.x, d = threadIdx.x;
    __shared__ float hs[HH];
    hs[d] = h[(size_t)j * HH + d];
    __syncthreads();
    float t = db1[d];
    for (int k = 0; k < HH; ++k) t += hs[k] * dw1[k * HH + d];
    t = fmaxf(t, 0.f);
    float sum = t * dw2[d];
#pragma unroll
    for (int o = 32; o; o >>= 1) sum += __shfl_xor(sum, o);
    if (d == 0) out[j] = sum + db2[0];
}

// ===========================================================================

extern "C" void kernel_launch(void* const* d_in, const int* in_sizes, int n_in,
                              void* d_out, int out_size, void* d_ws, size_t ws_size,
                              hipStream_t stream) {
    const float* x      = (const float*)d_in[0];
    const float* ea     = (const float*)d_in[1];
    const float* enc_w1 = (const float*)d_in[2];
    const float* enc_b1 = (const float*)d_in[3];
    const float* enc_w2 = (const float*)d_in[4];
    const float* enc_b2 = (const float*)d_in[5];
    const float* att_w1 = (const float*)d_in[6];
    const float* att_b1 = (const float*)d_in[7];
    const float* att_w2 = (const float*)d_in[8];
    // d_in[9] = att_b2: per-layer constant, cancels in softmax — unused
    const float* val_w1 = (const float*)d_in[10];
    const float* val_b1 = (const float*)d_in[11];
    const float* val_w2 = (const float*)d_in[12];
    const float* val_b2 = (const float*)d_in[13];
    const float* upd_w1 = (const float*)d_in[14];
    const float* upd_b1 = (const float*)d_in[15];
    const float* upd_w2 = (const float*)d_in[16];
    const float* upd_b2 = (const float*)d_in[17];
    const float* ln_g   = (const float*)d_in[18];
    const float* ln_b   = (const float*)d_in[19];
    const float* dec_w1 = (const float*)d_in[20];
    const float* dec_b1 = (const float*)d_in[21];
    const float* dec_w2 = (const float*)d_in[22];
    const float* dec_b2 = (const float*)d_in[23];
    // d_in[24] = edge_index: dense regular grid (src=e/N, dst=e%N) — used structurally

    const size_t NH = (size_t)NN * HH;
    float* ws = (float*)d_ws;

    // ---- primary: single cooperative kernel ----
    GnnParams P;
    P.x = x; P.ea = ea;
    P.ew1 = enc_w1; P.eb1 = enc_b1; P.ew2 = enc_w2; P.eb2 = enc_b2;
    P.aw1 = att_w1; P.ab1 = att_b1; P.aw2 = att_w2;
    P.vw1 = val_w1; P.vb1 = val_b1; P.vw2 = val_w2; P.vb2 = val_b2;
    P.uw1 = upd_w1; P.ub1 = upd_b1; P.uw2 = upd_w2; P.ub2 = upd_b2;
    P.lng = ln_g;  P.lnb = ln_b;
    P.dw1 = dec_w1; P.db1 = dec_b1; P.dw2 = dec_w2; P.db2 = dec_b2;
    P.Qs = ws; P.Rv = ws + NH; P.Sq = ws + 2 * NH;
    P.out = (float*)d_out;

    void* kargs[] = { (void*)&P };
    hipError_t rc = hipLaunchCooperativeKernel((const void*)k_fused, dim3(NN), dim3(256),
                                               kargs, 0, stream);
    if (rc == hipSuccess) return;

    // ---- fallback: validated multi-kernel pipeline (round 2) ----
    float* EAT  = ws;
    float* base = ws + (size_t)NN * NN * 6;
    float* h    = base;
    float* Pd   = h + NH;
    float* Qs   = Pd + NH;
    float* Rv   = Qs + NH;
    float* acc  = Rv + NH;
    float* h2   = acc + NH;
    float* Sq   = h2 + NH;

    k_transpose<<<(NN * NN) / 256, 256, 0, stream>>>(ea, EAT);
    k_encoder<<<NN, HH, 0, stream>>>(x, enc_w1, enc_b1, enc_w2, enc_b2,
                                     att_w1, att_b1, att_w2, val_w1, val_b1,
                                     h, Pd, Qs, Rv, Sq);
    const float* hin = h;
    float* hout = h2;
    for (int l = 0; l < NLAYERS; ++l) {
        const float* aw1 = att_w1 + (size_t)l * 134 * HH;
        const float* vw1 = val_w1 + (size_t)l * 70 * HH;
        k_edge_fb<<<NN, 256, 0, stream>>>(EAT, Pd, Qs, Rv, Sq,
                                          aw1 + 128 * HH, att_w2 + l * HH,
                                          vw1 + 64 * HH, acc);
        int np = (l + 1 < NLAYERS) ? (l + 1) : l;
        k_node_fb<<<NN, 256, 0, stream>>>(hin, acc,
                                          val_w2 + (size_t)l * HH * HH, val_b2 + l * HH,
                                          upd_w1 + (size_t)l * 2 * HH * HH, upd_b1 + l * HH,
                                          upd_w2 + (size_t)l * HH * HH, upd_b2 + l * HH,
                                          ln_g + l * HH, ln_b + l * HH,
                                          hout,
                                          att_w1 + (size_t)np * 134 * HH, att_b1 + np * HH,
                                          att_w2 + np * HH,
                                          val_w1 + (size_t)np * 70 * HH, val_b1 + np * HH,
                                          Pd, Qs, Rv, Sq, (l + 1 < NLAYERS) ? 1 : 0);
        float* tmp = (float*)hin; hin = hout; hout = tmp;
    }
    k_decoder<<<NN, HH, 0, stream>>>(hin, dec_w1, dec_b1, dec_w2, dec_b2, (float*)d_out);
}

// Round 4
// 213.295 us; speedup vs baseline: 2.1041x; 2.1041x over previous
//
#include <hip/hip_runtime.h>
#include <math.h>

#define NN 512
#define HH 64
#define NLAYERS 4
#define LN_EPS 1e-5f

// ---------------------------------------------------------------------------
// 7-dispatch pipeline, all validated algebra from round 2 (absmax 0.0):
//   k_transpose : ea (src-major) -> EAT (dst-major), coalesced writes
//   k_encoder   : h = MLP(x); prep Pd/Qs/Rv/Sq for layer 0   (buffer set 0)
//   k_layer x4  : edge phase (8 waves, dense softmax-attention over 512 srcs)
//                 + node phase (val_w2 pulled past aggregation, upd MLP, LN)
//                 + prep for next layer into the OTHER buffer set (no race:
//                 layer l reads set l&1, writes set (l+1)&1)
//   k_decoder   : out = MLP(h)
// Score algebra: leaky(z)=0.6z+0.4|z|; per-dst-constant terms cancel in
// softmax; ea-linear term contracted to w6s[6]; src-linear term = Sq[i].
// ---------------------------------------------------------------------------

__global__ void k_transpose(const float* __restrict__ ea, float* __restrict__ eat) {
    int t = blockIdx.x * 256 + threadIdx.x;      // t = j*NN + i (output index)
    int i = t & (NN - 1);
    int j = t >> 9;
    int e = i * NN + j;                          // edge (src=i, dst=j)
#pragma unroll
    for (int k = 0; k < 6; ++k) eat[(size_t)t * 6 + k] = ea[(size_t)e * 6 + k];
}

// 256 threads: encoder MLP + layer-0 prep, split-K across 4 waves.
__launch_bounds__(256)
__global__ void k_encoder(const float* __restrict__ x,
                          const float* __restrict__ ew1, const float* __restrict__ eb1,
                          const float* __restrict__ ew2, const float* __restrict__ eb2,
                          const float* __restrict__ aw1, const float* __restrict__ ab1,
                          const float* __restrict__ wa2, const float* __restrict__ vw1,
                          const float* __restrict__ vb1,
                          float* __restrict__ h, float* __restrict__ Pd,
                          float* __restrict__ Qs, float* __restrict__ Rv,
                          float* __restrict__ Sq) {
    const int j = blockIdx.x;
    const int tid = threadIdx.x;
    const int d = tid & 63;
    const int w = tid >> 6;        // 0..3
    __shared__ float r1[HH], hs[HH];
    __shared__ float part[4][HH], partQ[4][HH], partR[4][HH];

    if (w == 0) {
        float z = eb1[d];
#pragma unroll
        for (int k = 0; k < 6; ++k) z += x[j * 6 + k] * ew1[k * HH + d];
        r1[d] = fmaxf(z, 0.f);
    }
    __syncthreads();
    {
        float z2 = (w == 0) ? eb2[d] : 0.f;
        for (int k = w * 16; k < w * 16 + 16; ++k) z2 += r1[k] * ew2[k * HH + d];
        part[w][d] = z2;
    }
    __syncthreads();
    if (w == 0) {
        float hv = part[0][d] + part[1][d] + part[2][d] + part[3][d];
        h[(size_t)j * HH + d] = hv;
        hs[d] = hv;
    }
    __syncthreads();
    {
        float pp = (w == 0) ? ab1[d] : 0.f;
        float qq = 0.f;
        float rr = (w == 0) ? vb1[d] : 0.f;
        for (int k = w * 16; k < w * 16 + 16; ++k) {
            float hk = hs[k];
            pp += hk * aw1[k * HH + d];
            qq += hk * aw1[(HH + k) * HH + d];
            rr += hk * vw1[k * HH + d];
        }
        part[w][d] = pp; partQ[w][d] = qq; partR[w][d] = rr;
    }
    __syncthreads();
    if (w == 0) {
        float qf = partQ[0][d] + partQ[1][d] + partQ[2][d] + partQ[3][d];
        Pd[(size_t)j * HH + d] = part[0][d] + part[1][d] + part[2][d] + part[3][d];
        Qs[(size_t)j * HH + d] = qf;
        Rv[(size_t)j * HH + d] = partR[0][d] + partR[1][d] + partR[2][d] + partR[3][d];
        float sq = qf * wa2[d];
#pragma unroll
        for (int o = 32; o; o >>= 1) sq += __shfl_xor(sq, o);
        if (d == 0) Sq[j] = sq;
    }
}

// Layer kernel: 512 threads = 8 waves. Block j owns dst node j.
// Edge phase: each wave covers 64 srcs (8 iters of 8 srcs x 8 dim-parts).
// Node phase: split-K across 8 waves. Prep writes NEXT-layer buffer set.
__launch_bounds__(512, 4)
__global__ void k_layer(const float* __restrict__ eat, const float* __restrict__ h_in,
                        const float* __restrict__ Pd, const float* __restrict__ Qs,
                        const float* __restrict__ Rv, const float* __restrict__ Sq,
                        const float* __restrict__ waE,   // att_w1[l] rows 128..133 (6x64)
                        const float* __restrict__ wa2v,  // att_w2[l] (64)
                        const float* __restrict__ wvE,   // val_w1[l] rows 64..69 (6x64)
                        const float* __restrict__ wv2, const float* __restrict__ vb2,
                        const float* __restrict__ uw1, const float* __restrict__ ub1,
                        const float* __restrict__ uw2, const float* __restrict__ ub2,
                        const float* __restrict__ lng, const float* __restrict__ lnb,
                        float* __restrict__ h_out,
                        const float* __restrict__ aw1n, const float* __restrict__ ab1n,
                        const float* __restrict__ wa2n, const float* __restrict__ vw1n,
                        const float* __restrict__ vb1n,
                        float* __restrict__ Pdn, float* __restrict__ Qsn,
                        float* __restrict__ Rvn, float* __restrict__ Sqn,
                        int do_prep) {
    const int j = blockIdx.x;
    const int tid = threadIdx.x;
    const int lane = tid & 63;
    const int w = tid >> 6;        // wave 0..7
    const int slot = lane >> 3;    // 0..7 (src sub-index)
    const int dp = lane & 7;       // 0..7 (dim part)
    const int d0 = dp * 8;
    const int d = lane;

    __shared__ __align__(16) float ea_s[NN * 6];   // 12 KB
    __shared__ __align__(16) float Sq_s[NN];
    __shared__ float a_s[NN];
    __shared__ float red_m[8], red_s[8];
    __shared__ float accs[8][HH];
    __shared__ float av[HH], uin[2 * HH], r1[HH], hs[HH];
    __shared__ float part[8][HH], partQ[8][HH], partR[8][HH];

    // ---- stage: ea (coalesced, 768 float4), Sq (128 float4) ----
    {
        const float4* s4 = (const float4*)(eat + (size_t)j * (NN * 6));
        float4* d4 = (float4*)ea_s;
        d4[tid] = s4[tid];
        if (tid < 256) d4[tid + 512] = s4[tid + 512];
    }
    if (tid < 128) ((float4*)Sq_s)[tid] = ((const float4*)Sq)[tid];

    // ---- per-lane weight registers ----
    float WA[6][8], wa2raw[8], wa2r[8], pdr[8], w6s[6];
#pragma unroll
    for (int k = 0; k < 6; ++k)
#pragma unroll
        for (int u = 0; u < 8; ++u) WA[k][u] = waE[k * HH + d0 + u];
#pragma unroll
    for (int u = 0; u < 8; ++u) {
        wa2raw[u] = wa2v[d0 + u];
        pdr[u] = Pd[(size_t)j * HH + d0 + u];
    }
#pragma unroll
    for (int k = 0; k < 6; ++k) {
        float t = 0.f;
#pragma unroll
        for (int u = 0; u < 8; ++u) t += WA[k][u] * wa2raw[u];
        t += __shfl_xor(t, 1);
        t += __shfl_xor(t, 2);
        t += __shfl_xor(t, 4);
        w6s[k] = 0.6f * t;
    }
#pragma unroll
    for (int u = 0; u < 8; ++u) wa2r[u] = 0.4f * wa2raw[u];
    __syncthreads();

    // ---- phase 1: scores for this wave's 64 srcs ----
    const int ibw = w * 64;
    float lmax = -1e30f;
#pragma unroll
    for (int it = 0; it < 8; ++it) {
        const int i = ibw + it * 8 + slot;
        const float4* q4 = (const float4*)(Qs + (size_t)i * HH + d0);
        float4 qa = q4[0], qb = q4[1];
        float qv[8] = {qa.x, qa.y, qa.z, qa.w, qb.x, qb.y, qb.z, qb.w};
        float eav[6];
#pragma unroll
        for (int k = 0; k < 6; ++k) eav[k] = ea_s[i * 6 + k];
        float p1 = 0.f;
#pragma unroll
        for (int u = 0; u < 8; ++u) {
            float z = pdr[u] + qv[u];
#pragma unroll
            for (int k = 0; k < 6; ++k) z += eav[k] * WA[k][u];
            p1 += fabsf(z) * wa2r[u];
        }
        p1 += __shfl_xor(p1, 1);
        p1 += __shfl_xor(p1, 2);
        p1 += __shfl_xor(p1, 4);
        float lin = 0.6f * Sq_s[i];
#pragma unroll
        for (int k = 0; k < 6; ++k) lin += eav[k] * w6s[k];
        float a = lin + p1;
        if (dp == 0) a_s[i] = a;
        lmax = fmaxf(lmax, a);
    }
#pragma unroll
    for (int o = 32; o; o >>= 1) lmax = fmaxf(lmax, __shfl_xor(lmax, o));
    if (lane == 0) red_m[w] = lmax;
    __syncthreads();
    float m = red_m[0];
#pragma unroll
    for (int q = 1; q < 8; ++q) m = fmaxf(m, red_m[q]);

    // ---- exp + sum (512 entries, 1 per thread) ----
    float e = expf(a_s[tid] - m);
    a_s[tid] = e;
    float lsum = e;
#pragma unroll
    for (int o = 32; o; o >>= 1) lsum += __shfl_xor(lsum, o);
    if (lane == 0) red_s[w] = lsum;
    __syncthreads();
    float s = red_s[0];
#pragma unroll
    for (int q = 1; q < 8; ++q) s += red_s[q];

    // ---- phase 2: weighted aggregate of relu(value-layer-1) ----
    float WV[6][8];   // deferred load keeps phase-1 register pressure low
#pragma unroll
    for (int k = 0; k < 6; ++k)
#pragma unroll
        for (int u = 0; u < 8; ++u) WV[k][u] = wvE[k * HH + d0 + u];
    float acc[8] = {0.f, 0.f, 0.f, 0.f, 0.f, 0.f, 0.f, 0.f};
#pragma unroll
    for (int it = 0; it < 8; ++it) {
        const int i = ibw + it * 8 + slot;
        const float4* r4 = (const float4*)(Rv + (size_t)i * HH + d0);
        float4 ra = r4[0], rb = r4[1];
        float rv[8] = {ra.x, ra.y, ra.z, ra.w, rb.x, rb.y, rb.z, rb.w};
        float eav[6];
#pragma unroll
        for (int k = 0; k < 6; ++k) eav[k] = ea_s[i * 6 + k];
        const float wi = a_s[i];
#pragma unroll
        for (int u = 0; u < 8; ++u) {
            float z = rv[u];
#pragma unroll
            for (int k = 0; k < 6; ++k) z += eav[k] * WV[k][u];
            acc[u] += wi * fmaxf(z, 0.f);
        }
    }
#pragma unroll
    for (int u = 0; u < 8; ++u) {
        acc[u] += __shfl_xor(acc[u], 8);
        acc[u] += __shfl_xor(acc[u], 16);
        acc[u] += __shfl_xor(acc[u], 32);
    }
    if (slot == 0) {
#pragma unroll
        for (int u = 0; u < 8; ++u) accs[w][d0 + u] = acc[u];
    }
    __syncthreads();
    if (tid < HH) {
        float tot = accs[0][tid];
#pragma unroll
        for (int q = 1; q < 8; ++q) tot += accs[q][tid];
        av[tid] = tot / s;
    }
    __syncthreads();

    // ---- node phase (split-K over 8 waves) ----
    const float hv = h_in[(size_t)j * HH + d];
    {
        float p = (w == 0) ? vb2[d] : 0.f;
        for (int k = w * 8; k < w * 8 + 8; ++k) p += av[k] * wv2[k * HH + d];
        part[w][d] = p;
        if (w == 0) uin[d] = hv;
    }
    __syncthreads();
    if (w == 0) {
        float agg = part[0][d];
#pragma unroll
        for (int q = 1; q < 8; ++q) agg += part[q][d];
        uin[HH + d] = agg;
    }
    __syncthreads();
    {
        float t = (w == 0) ? ub1[d] : 0.f;
        for (int c = w * 16; c < w * 16 + 16; ++c) t += uin[c] * uw1[c * HH + d];
        part[w][d] = t;
    }
    __syncthreads();
    if (w == 0) {
        float t = part[0][d];
#pragma unroll
        for (int q = 1; q < 8; ++q) t += part[q][d];
        r1[d] = fmaxf(t, 0.f);
    }
    __syncthreads();
    {
        float u = (w == 0) ? ub2[d] : 0.f;
        for (int k = w * 8; k < w * 8 + 8; ++k) u += r1[k] * uw2[k * HH + d];
        part[w][d] = u;
    }
    __syncthreads();
    if (w == 0) {
        float r = hv + part[0][d];
#pragma unroll
        for (int q = 1; q < 8; ++q) r += part[q][d];
        float sum = r;
#pragma unroll
        for (int o = 32; o; o >>= 1) sum += __shfl_xor(sum, o);
        float mu = sum * (1.f / HH);
        float dr = r - mu;
        float v2 = dr * dr;
#pragma unroll
        for (int o = 32; o; o >>= 1) v2 += __shfl_xor(v2, o);
        float var = v2 * (1.f / HH);
        float hn = lng[d] * dr * (1.f / sqrtf(var + LN_EPS)) + lnb[d];
        h_out[(size_t)j * HH + d] = hn;
        hs[d] = hn;
    }
    __syncthreads();

    if (do_prep) {
        float pp = (w == 0) ? ab1n[d] : 0.f;
        float qq = 0.f;
        float rr = (w == 0) ? vb1n[d] : 0.f;
        for (int k = w * 8; k < w * 8 + 8; ++k) {
            float hk = hs[k];
            pp += hk * aw1n[k * HH + d];
            qq += hk * aw1n[(HH + k) * HH + d];
            rr += hk * vw1n[k * HH + d];
        }
        part[w][d] = pp; partQ[w][d] = qq; partR[w][d] = rr;
        __syncthreads();
        if (w == 0) {
            float pf = part[0][d], qf = partQ[0][d], rf = partR[0][d];
#pragma unroll
            for (int q = 1; q < 8; ++q) {
                pf += part[q][d]; qf += partQ[q][d]; rf += partR[q][d];
            }
            Pdn[(size_t)j * HH + d] = pf;
            Qsn[(size_t)j * HH + d] = qf;
            Rvn[(size_t)j * HH + d] = rf;
            float sq = qf * wa2n[d];
#pragma unroll
            for (int o = 32; o; o >>= 1) sq += __shfl_xor(sq, o);
            if (d == 0) Sqn[j] = sq;
        }
    }
}

__launch_bounds__(256)
__global__ void k_decoder(const float* __restrict__ h,
                          const float* __restrict__ dw1, const float* __restrict__ db1,
                          const float* __restrict__ dw2, const float* __restrict__ db2,
                          float* __restrict__ out) {
    const int j = blockIdx.x;
    const int tid = threadIdx.x;
    const int d = tid & 63;
    const int w = tid >> 6;
    __shared__ float hs[HH], part[4][HH];
    if (w == 0) hs[d] = h[(size_t)j * HH + d];
    __syncthreads();
    float t = (w == 0) ? db1[d] : 0.f;
    for (int k = w * 16; k < w * 16 + 16; ++k) t += hs[k] * dw1[k * HH + d];
    part[w][d] = t;
    __syncthreads();
    if (w == 0) {
        float tt = fmaxf(part[0][d] + part[1][d] + part[2][d] + part[3][d], 0.f);
        float sum = tt * dw2[d];
#pragma unroll
        for (int o = 32; o; o >>= 1) sum += __shfl_xor(sum, o);
        if (d == 0) out[j] = sum + db2[0];
    }
}

extern "C" void kernel_launch(void* const* d_in, const int* in_sizes, int n_in,
                              void* d_out, int out_size, void* d_ws, size_t ws_size,
                              hipStream_t stream) {
    const float* x      = (const float*)d_in[0];
    const float* ea     = (const float*)d_in[1];
    const float* enc_w1 = (const float*)d_in[2];
    const float* enc_b1 = (const float*)d_in[3];
    const float* enc_w2 = (const float*)d_in[4];
    const float* enc_b2 = (const float*)d_in[5];
    const float* att_w1 = (const float*)d_in[6];
    const float* att_b1 = (const float*)d_in[7];
    const float* att_w2 = (const float*)d_in[8];
    // d_in[9] = att_b2: per-layer constant, cancels in softmax — unused
    const float* val_w1 = (const float*)d_in[10];
    const float* val_b1 = (const float*)d_in[11];
    const float* val_w2 = (const float*)d_in[12];
    const float* val_b2 = (const float*)d_in[13];
    const float* upd_w1 = (const float*)d_in[14];
    const float* upd_b1 = (const float*)d_in[15];
    const float* upd_w2 = (const float*)d_in[16];
    const float* upd_b2 = (const float*)d_in[17];
    const float* ln_g   = (const float*)d_in[18];
    const float* ln_b   = (const float*)d_in[19];
    const float* dec_w1 = (const float*)d_in[20];
    const float* dec_b1 = (const float*)d_in[21];
    const float* dec_w2 = (const float*)d_in[22];
    const float* dec_b2 = (const float*)d_in[23];
    // d_in[24] = edge_index: dense regular grid (src=e/N, dst=e%N) — used structurally

    const size_t NH = (size_t)NN * HH;
    float* ws   = (float*)d_ws;
    float* EAT  = ws;                              // NN*NN*6
    float* h0   = EAT + (size_t)NN * NN * 6;
    float* h1   = h0 + NH;
    float* Pd0  = h1 + NH;
    float* Pd1  = Pd0 + NH;
    float* Qs0  = Pd1 + NH;
    float* Qs1  = Qs0 + NH;
    float* Rv0  = Qs1 + NH;
    float* Rv1  = Rv0 + NH;
    float* Sq0  = Rv1 + NH;
    float* Sq1  = Sq0 + NN;

    float* Pdb[2] = {Pd0, Pd1};
    float* Qsb[2] = {Qs0, Qs1};
    float* Rvb[2] = {Rv0, Rv1};
    float* Sqb[2] = {Sq0, Sq1};
    float* hb[2]  = {h0, h1};

    k_transpose<<<(NN * NN) / 256, 256, 0, stream>>>(ea, EAT);
    k_encoder<<<NN, 256, 0, stream>>>(x, enc_w1, enc_b1, enc_w2, enc_b2,
                                      att_w1, att_b1, att_w2, val_w1, val_b1,
                                      h0, Pd0, Qs0, Rv0, Sq0);

    for (int l = 0; l < NLAYERS; ++l) {
        const int cur = l & 1, nxt = (l + 1) & 1;
        const int np = (l + 1 < NLAYERS) ? (l + 1) : l;   // clamped; unused if do_prep=0
        const float* aw1 = att_w1 + (size_t)l * 134 * HH;
        const float* vw1 = val_w1 + (size_t)l * 70 * HH;
        k_layer<<<NN, 512, 0, stream>>>(
            EAT, hb[cur],
            Pdb[cur], Qsb[cur], Rvb[cur], Sqb[cur],
            aw1 + 128 * HH, att_w2 + l * HH, vw1 + 64 * HH,
            val_w2 + (size_t)l * HH * HH, val_b2 + l * HH,
            upd_w1 + (size_t)l * 2 * HH * HH, upd_b1 + l * HH,
            upd_w2 + (size_t)l * HH * HH, upd_b2 + l * HH,
            ln_g + l * HH, ln_b + l * HH,
            hb[nxt],
            att_w1 + (size_t)np * 134 * HH, att_b1 + np * HH, att_w2 + np * HH,
            val_w1 + (size_t)np * 70 * HH, val_b1 + np * HH,
            Pdb[nxt], Qsb[nxt], Rvb[nxt], Sqb[nxt],
            (l + 1 < NLAYERS) ? 1 : 0);
    }
    k_decoder<<<NN, 256, 0, stream>>>(hb[NLAYERS & 1], dec_w1, dec_b1, dec_w2, dec_b2,
                                      (float*)d_out);
}